// Round 1
// baseline (504.709 us; speedup 1.0000x reference)
//
#include <hip/hip_runtime.h>

#define N_POINTS 500000
#define K_CENT   512
#define W_DIM    64

// Precompute ||c||^2 per centroid in double (a per-centroid constant bias in d2
// must be < ~1e-6 so it can't flip argmin on near-tie points).
__global__ void c2_kernel(const float* __restrict__ cb, float* __restrict__ c2) {
    int c = blockIdx.x * blockDim.x + threadIdx.x;
    if (c < K_CENT) {
        const float4* row = reinterpret_cast<const float4*>(cb + (size_t)c * W_DIM);
        double s = 0.0;
#pragma unroll
        for (int j = 0; j < W_DIM / 4; ++j) {
            float4 v = row[j];
            s += (double)v.x * v.x + (double)v.y * v.y + (double)v.z * v.z + (double)v.w * v.w;
        }
        c2[c] = (float)s;
    }
}

__global__ __launch_bounds__(256, 4)
void kmeans_assign(const float* __restrict__ X,
                   const float* __restrict__ cb,
                   const float* __restrict__ c2,
                   float* __restrict__ out_idx,
                   float* __restrict__ out_dist) {
    int i = blockIdx.x * blockDim.x + threadIdx.x;
    if (i >= N_POINTS) return;

    // Own row in registers (64 VGPRs), vectorized 16B loads.
    float x[W_DIM];
    const float4* xr = reinterpret_cast<const float4*>(X + (size_t)i * W_DIM);
#pragma unroll
    for (int j = 0; j < W_DIM / 4; ++j) {
        float4 v = xr[j];
        x[4 * j + 0] = v.x; x[4 * j + 1] = v.y;
        x[4 * j + 2] = v.z; x[4 * j + 3] = v.w;
    }
    float x2 = 0.f;
#pragma unroll
    for (int j = 0; j < W_DIM; ++j) x2 = fmaf(x[j], x[j], x2);

    float best_d = 3.4e38f;
    int   best_i = 0;

    // Codebook accesses are wave-uniform -> scalar loads (SGPR operand in FMA).
    // 2 centroids x 2 dim-partials = 4 independent FMA chains for ILP.
    for (int c = 0; c < K_CENT; c += 2) {
        const float* c0 = cb + (size_t)c * W_DIM;
        const float* c1 = c0 + W_DIM;
        float a00 = 0.f, a01 = 0.f, a10 = 0.f, a11 = 0.f;
#pragma unroll
        for (int k = 0; k < W_DIM; k += 2) {
            a00 = fmaf(x[k],     c0[k],     a00);
            a01 = fmaf(x[k + 1], c0[k + 1], a01);
            a10 = fmaf(x[k],     c1[k],     a10);
            a11 = fmaf(x[k + 1], c1[k + 1], a11);
        }
        float dot0 = a00 + a01;
        float dot1 = a10 + a11;
        // Match reference: (x2 - 2*dot) + c2
        float d0 = (x2 - 2.f * dot0) + c2[c];
        float d1 = (x2 - 2.f * dot1) + c2[c + 1];
        // strict < scanning ascending c == argmin first-index tie-break
        if (d0 < best_d) { best_d = d0; best_i = c; }
        if (d1 < best_d) { best_d = d1; best_i = c + 1; }
    }

    out_idx[i]  = (float)best_i;
    out_dist[i] = sqrtf(fmaxf(best_d, 0.f));
}

extern "C" void kernel_launch(void* const* d_in, const int* in_sizes, int n_in,
                              void* d_out, int out_size, void* d_ws, size_t ws_size,
                              hipStream_t stream) {
    const float* X  = (const float*)d_in[0];
    const float* cb = (const float*)d_in[1];
    float* out      = (float*)d_out;
    float* c2       = (float*)d_ws;   // 512 floats of scratch

    hipLaunchKernelGGL(c2_kernel, dim3((K_CENT + 255) / 256), dim3(256), 0, stream, cb, c2);

    int grid = (N_POINTS + 255) / 256;
    hipLaunchKernelGGL(kmeans_assign, dim3(grid), dim3(256), 0, stream,
                       X, cb, c2, out, out + N_POINTS);
}

// Round 2
// 252.723 us; speedup vs baseline: 1.9971x; 1.9971x over previous
//
#include <hip/hip_runtime.h>

#define N_POINTS 500000
#define K_CENT   512
#define W_DIM    64
#define N_TILES  (N_POINTS / 32)   // 15625, exact
#define SCALE_LO 2048.0f           // 2^11
#define INV_LO   (1.0f / 2048.0f)

typedef _Float16 half8 __attribute__((ext_vector_type(8)));
typedef float    f32x16 __attribute__((ext_vector_type(16)));

// ---- pre-kernel 1: codebook -> f16 hi/lo of w = -2*c (lo pre-scaled by 2^11)
__global__ void cvt_kernel(const float* __restrict__ cb,
                           _Float16* __restrict__ cb_h,
                           _Float16* __restrict__ cb_l) {
    int id = blockIdx.x * 256 + threadIdx.x;           // 512*8 = 4096 ids
    if (id >= K_CENT * 8) return;
    int c = id >> 3, o = (id & 7) * 8;
    const float* src = cb + (size_t)c * W_DIM + o;
    half8 h, l;
#pragma unroll
    for (int j = 0; j < 8; ++j) {
        float w = -2.0f * src[j];
        _Float16 hh = (_Float16)w;                     // RNE
        h[j] = hh;
        l[j] = (_Float16)((w - (float)hh) * SCALE_LO); // residual, scaled up
    }
    *(half8*)(cb_h + (size_t)c * W_DIM + o) = h;
    *(half8*)(cb_l + (size_t)c * W_DIM + o) = l;
}

// ---- pre-kernel 2: c2[c] = ||c||^2 in double (deterministic, no atomics)
__global__ void c2_kernel(const float* __restrict__ cb, float* __restrict__ c2) {
    int c = blockIdx.x * 256 + threadIdx.x;
    if (c >= K_CENT) return;
    const float4* row = (const float4*)(cb + (size_t)c * W_DIM);
    double s = 0.0;
#pragma unroll
    for (int j = 0; j < W_DIM / 4; ++j) {
        float4 v = row[j];
        s += (double)v.x * v.x + (double)v.y * v.y + (double)v.z * v.z + (double)v.w * v.w;
    }
    c2[c] = (float)s;
}

// ---- main kernel: per wave, one 32-point tile vs all 512 centroids.
// A = codebook chunk (32 cent x 16 dims), B = X tile (16 dims x 32 points).
// mfma_f32_32x32x16_f16: A lane l: row=l&31, k=(l>>5)*8+j ; B lane l: col=l&31,
// k=(l>>5)*8+j ; C/D lane l: col=l&31, row=(reg&3)+8*(reg>>2)+4*(l>>5).
__global__ __launch_bounds__(256, 3)
void kmeans_mfma(const float* __restrict__ X,
                 const _Float16* __restrict__ cb_h,
                 const _Float16* __restrict__ cb_l,
                 const float* __restrict__ c2,
                 float* __restrict__ out_idx,
                 float* __restrict__ out_dist) {
    __shared__ float c2s[K_CENT];
    int tid  = threadIdx.x;
    c2s[tid] = c2[tid];
    c2s[tid + 256] = c2[tid + 256];
    __syncthreads();

    int lane = tid & 63;
    int wave = tid >> 6;
    int half = lane >> 5;      // 0/1
    int l31  = lane & 31;
    int kb   = half * 8;       // k-offset within a K=16 step

    int tile = blockIdx.x * 4 + wave;
    if (tile >= N_TILES) return;
    int p = tile * 32 + l31;   // this lane's point (col)

    // ---- load X fragments (B operand), convert fp32 -> f16 hi + scaled lo
    half8 bh[4], bl[4];
    float x2p = 0.f;
#pragma unroll
    for (int s = 0; s < 4; ++s) {
        const float4* xp = (const float4*)(X + (size_t)p * W_DIM + s * 16 + kb);
        float4 f0 = xp[0], f1 = xp[1];
        float f[8] = {f0.x, f0.y, f0.z, f0.w, f1.x, f1.y, f1.z, f1.w};
#pragma unroll
        for (int j = 0; j < 8; ++j) {
            _Float16 hh = (_Float16)f[j];
            bh[s][j] = hh;
            bl[s][j] = (_Float16)((f[j] - (float)hh) * SCALE_LO);
            x2p = fmaf(f[j], f[j], x2p);
        }
    }
    // full ||x||^2: halves hold disjoint dim sets of the same point
    x2p += __shfl_xor(x2p, 32);

    float best_d = 3.4e38f;
    int   best_i = 0;

    // A-fragment double buffers
    half8 ah[2][4], al[2][4];
    const _Float16* ab_h = cb_h + (size_t)l31 * W_DIM + kb;
    const _Float16* ab_l = cb_l + (size_t)l31 * W_DIM + kb;
#pragma unroll
    for (int s = 0; s < 4; ++s) {
        ah[0][s] = *(const half8*)(ab_h + s * 16);
        al[0][s] = *(const half8*)(ab_l + s * 16);
    }

#pragma unroll
    for (int t = 0; t < 16; ++t) {
        int cur = t & 1, nxt = cur ^ 1;
        if (t < 15) {
            const _Float16* nh = ab_h + (size_t)(t + 1) * 32 * W_DIM;
            const _Float16* nl = ab_l + (size_t)(t + 1) * 32 * W_DIM;
#pragma unroll
            for (int s = 0; s < 4; ++s) {
                ah[nxt][s] = *(const half8*)(nh + s * 16);
                al[nxt][s] = *(const half8*)(nl + s * 16);
            }
        }
        // acc init: main <- c2 of this chunk's rows; cross <- 0
        float4 q0 = *(const float4*)&c2s[t * 32 + half * 4 + 0];
        float4 q1 = *(const float4*)&c2s[t * 32 + half * 4 + 8];
        float4 q2 = *(const float4*)&c2s[t * 32 + half * 4 + 16];
        float4 q3 = *(const float4*)&c2s[t * 32 + half * 4 + 24];
        f32x16 accm, accc;
        accm[0]=q0.x; accm[1]=q0.y; accm[2]=q0.z; accm[3]=q0.w;
        accm[4]=q1.x; accm[5]=q1.y; accm[6]=q1.z; accm[7]=q1.w;
        accm[8]=q2.x; accm[9]=q2.y; accm[10]=q2.z; accm[11]=q2.w;
        accm[12]=q3.x; accm[13]=q3.y; accm[14]=q3.z; accm[15]=q3.w;
#pragma unroll
        for (int j = 0; j < 16; ++j) accc[j] = 0.f;

#pragma unroll
        for (int s = 0; s < 4; ++s) {
            accm = __builtin_amdgcn_mfma_f32_32x32x16_f16(ah[cur][s], bh[s], accm, 0, 0, 0);
            accc = __builtin_amdgcn_mfma_f32_32x32x16_f16(al[cur][s], bh[s], accc, 0, 0, 0);
            accc = __builtin_amdgcn_mfma_f32_32x32x16_f16(ah[cur][s], bl[s], accc, 0, 0, 0);
        }
        // argmin update: acc reg j -> centroid t*32 + 4*half + 8*(j>>2) + (j&3)
#pragma unroll
        for (int j = 0; j < 16; ++j) {
            float v = fmaf(accc[j], INV_LO, accm[j]);   // d2 - x2
            int ci = t * 32 + half * 4 + (j >> 2) * 8 + (j & 3);
            if (v < best_d) { best_d = v; best_i = ci; }   // strict <: first-index wins
        }
    }

    // combine the two lane-halves (disjoint centroid rows of the same point)
    float od = __shfl_xor(best_d, 32);
    int   oi = __shfl_xor(best_i, 32);
    if (od < best_d || (od == best_d && oi < best_i)) { best_d = od; best_i = oi; }

    if (half == 0) {
        out_idx[p]  = (float)best_i;
        out_dist[p] = sqrtf(fmaxf(best_d + x2p, 0.f));
    }
}

extern "C" void kernel_launch(void* const* d_in, const int* in_sizes, int n_in,
                              void* d_out, int out_size, void* d_ws, size_t ws_size,
                              hipStream_t stream) {
    const float* X  = (const float*)d_in[0];
    const float* cb = (const float*)d_in[1];
    float* out      = (float*)d_out;

    // workspace layout: cb_h 64KB | cb_l 64KB | c2 2KB
    _Float16* cb_h = (_Float16*)d_ws;
    _Float16* cb_l = cb_h + (size_t)K_CENT * W_DIM;
    float*    c2   = (float*)(cb_l + (size_t)K_CENT * W_DIM);

    hipLaunchKernelGGL(cvt_kernel, dim3((K_CENT * 8 + 255) / 256), dim3(256), 0, stream, cb, cb_h, cb_l);
    hipLaunchKernelGGL(c2_kernel, dim3((K_CENT + 255) / 256), dim3(256), 0, stream, cb, c2);

    int grid = (N_TILES + 3) / 4;   // 4 waves (tiles) per 256-thread block
    hipLaunchKernelGGL(kmeans_mfma, dim3(grid), dim3(256), 0, stream,
                       X, cb_h, cb_l, c2, out, out + N_POINTS);
}